// Round 1
// baseline (62.503 us; speedup 1.0000x reference)
//
#include <hip/hip_runtime.h>

#define N_NODES 640
#define NWORDS  20    // 640 / 32
#define H       64

// ---------------- K2: build adjacency bitmask from edge list ----------------
__global__ void build_bits(const int* __restrict__ ei, int E, unsigned* __restrict__ bits) {
    int i = blockIdx.x * blockDim.x + threadIdx.x;
    if (i >= E) return;
    int a = ei[i];
    int b = ei[i + E];
    if (a != b) atomicOr(&bits[a * NWORDS + (b >> 5)], 1u << (b & 31));
}

// ---------------- K3: per-node ego computation ----------------
// block = node v, 256 threads = 4 waves; each wave processes one neighbor u at a time.
__global__ __launch_bounds__(256) void rnp_main(
    const float* __restrict__ x,
    const float* __restrict__ W1a, const float* __restrict__ b1a,
    const float* __restrict__ W1b, const float* __restrict__ b1b,
    const float* __restrict__ W0a, const float* __restrict__ b0a,
    const float* __restrict__ W0b, const float* __restrict__ b0b,
    const unsigned* __restrict__ bits,
    float* __restrict__ out)
{
    __shared__ float sW1a[66 * 64];      // row-major [k][j]
    __shared__ float sW1b[64 * 65];      // row-major [d][e]
    __shared__ float sb1a[64];
    __shared__ float sb1b[65];
    __shared__ unsigned rowv[NWORDS];
    __shared__ unsigned short ulist[N_NODES];
    __shared__ int s_deg;
    __shared__ float agg[72];            // 65 used, padded
    __shared__ float inbuf[4][64];       // per-wave activation broadcast
    __shared__ float hbuf[4][64];        // per-wave hidden transpose

    const int v    = blockIdx.x;
    const int t    = threadIdx.x;
    const int lane = t & 63;
    const int wave = t >> 6;

    for (int i = t; i < 66 * 64; i += 256) sW1a[i] = W1a[i];
    for (int i = t; i < 64 * 65; i += 256) sW1b[i] = W1b[i];
    if (t < 64) sb1a[t] = b1a[t];
    if (t < 65) sb1b[t] = b1b[t];
    if (t < NWORDS) rowv[t] = bits[v * NWORDS + t];
    if (t < 72) agg[t] = 0.f;
    __syncthreads();

    if (t == 0) {
        int d = 0;
        for (int j = 0; j < NWORDS; ++j) {
            unsigned c = rowv[j];
            while (c) {
                int b = __ffs(c) - 1;
                ulist[d++] = (unsigned short)(j * 32 + b);
                c &= c - 1;
            }
        }
        s_deg = d;
    }
    __syncthreads();

    const int deg   = s_deg;
    const int niter = (deg + 3) >> 2;   // uniform trip count across waves

    for (int it = 0; it < niter; ++it) {
        const int  idx    = it * 4 + wave;
        const bool active = idx < deg;          // wave-uniform

        int   cnt  = 0;
        if (active) {
            const int u = ulist[idx];
            // ---- common neighbors: S2 = N(v) & N(u); gather cnt and sum_w x[w,lane]
            float xsum = 0.f;
            for (int j = 0; j < NWORDS; ++j) {
                unsigned c = rowv[j] & bits[u * NWORDS + j];
                cnt += __popc(c);
                while (c) {
                    int w = j * 32 + (__ffs(c) - 1);
                    c &= c - 1;
                    xsum += x[w * H + lane];
                }
            }
            inbuf[wave][lane] = x[u * H + lane] + xsum;   // inp1[0..63]
        }
        asm volatile("s_waitcnt lgkmcnt(0)" ::: "memory");

        if (active) {
            // ---- stage 1: h[j] = relu(b1a[j] + sum_k inp1[k] * W1a[k][j]), j = lane
            const float fcnt = (float)cnt;
            float h = sb1a[lane]
                    + (1.f + fcnt) * sW1a[64 * 64 + lane]
                    + fcnt         * sW1a[65 * 64 + lane];
            #pragma unroll 8
            for (int k = 0; k < 64; ++k)
                h += inbuf[wave][k] * sW1a[k * 64 + lane];
            h = fmaxf(h, 0.f);
            hbuf[wave][lane] = h;
        }
        asm volatile("s_waitcnt lgkmcnt(0)" ::: "memory");

        if (active) {
            // ---- stage 2: out1[e] = b1b[e] + sum_d h[d] * W1b[d][e], e = lane (+ e=64 via reduce)
            float o = sb1b[lane];
            #pragma unroll 8
            for (int d = 0; d < 64; ++d)
                o += hbuf[wave][d] * sW1b[d * 65 + lane];

            float p = hbuf[wave][lane] * sW1b[lane * 65 + 64];
            #pragma unroll
            for (int off = 32; off; off >>= 1) p += __shfl_xor(p, off, 64);

            atomicAdd(&agg[lane], o);
            if (lane == 0) atomicAdd(&agg[64], p + sb1b[64]);
        }
    }
    __syncthreads();

    // ---- MLP0 on wave 0: out = relu((hv+agg) @ W0a + b0a) @ W0b + b0b
    if (wave == 0) {
        inbuf[0][lane] = agg[lane] + x[v * H + lane];   // inp0[0..63]; inp0[64] = agg[64]
        asm volatile("s_waitcnt lgkmcnt(0)" ::: "memory");

        float h = b0a[lane] + agg[64] * W0a[64 * 64 + lane];
        #pragma unroll 8
        for (int k = 0; k < 64; ++k)
            h += inbuf[0][k] * W0a[k * 64 + lane];
        h = fmaxf(h, 0.f);
        hbuf[0][lane] = h;
        asm volatile("s_waitcnt lgkmcnt(0)" ::: "memory");

        float o = b0b[lane];
        #pragma unroll 8
        for (int d = 0; d < 64; ++d)
            o += hbuf[0][d] * W0b[d * 64 + lane];
        out[v * H + lane] = o;
    }
}

extern "C" void kernel_launch(void* const* d_in, const int* in_sizes, int n_in,
                              void* d_out, int out_size, void* d_ws, size_t ws_size,
                              hipStream_t stream) {
    const float* x   = (const float*)d_in[0];
    const float* W1a = (const float*)d_in[1];
    const float* b1a = (const float*)d_in[2];
    const float* W1b = (const float*)d_in[3];
    const float* b1b = (const float*)d_in[4];
    const float* W0a = (const float*)d_in[5];
    const float* b0a = (const float*)d_in[6];
    const float* W0b = (const float*)d_in[7];
    const float* b0b = (const float*)d_in[8];
    const int*   ei  = (const int*)d_in[9];
    const int    E   = in_sizes[9] / 2;

    unsigned* bits = (unsigned*)d_ws;
    hipMemsetAsync(bits, 0, N_NODES * NWORDS * sizeof(unsigned), stream);
    build_bits<<<(E + 255) / 256, 256, 0, stream>>>(ei, E, bits);
    rnp_main<<<N_NODES, 256, 0, stream>>>(x, W1a, b1a, W1b, b1b,
                                          W0a, b0a, W0b, b0b,
                                          bits, (float*)d_out);
}

// Round 2
// 34.584 us; speedup vs baseline: 1.8073x; 1.8073x over previous
//
#include <hip/hip_runtime.h>

#define NN 640
#define NW 20    // 640/32 bitmask words per node
#define H  64

// ---------------- K0: zero bits + xa = x @ W1a (per-node projection) ----------------
// grid 160 x 256: one wave per node (4 nodes/block); threads also zero the bitmask.
__global__ __launch_bounds__(256) void init_xa(const float* __restrict__ x,
                                               const float* __restrict__ W1a,
                                               unsigned* __restrict__ bits,
                                               float* __restrict__ xa) {
    int t = blockIdx.x * 256 + threadIdx.x;
    if (t < NN * NW) bits[t] = 0u;
    int n = blockIdx.x * 4 + (threadIdx.x >> 6);
    int lane = threadIdx.x & 63;
    float xv = x[n * H + lane];
    float acc = 0.f;
    #pragma unroll
    for (int k = 0; k < H; ++k)
        acc += __shfl(xv, k, 64) * W1a[k * H + lane];
    xa[n * H + lane] = acc;
}

// ---------------- K1: adjacency bitmask from edge list ----------------
__global__ void build_bits(const int* __restrict__ ei, int E, unsigned* __restrict__ bits) {
    int i = blockIdx.x * blockDim.x + threadIdx.x;
    if (i >= E) return;
    int a = ei[i];
    int b = ei[i + E];
    if (a != b) atomicOr(&bits[a * NW + (b >> 5)], 1u << (b & 31));
}

// ---------------- K2: per-pair hidden accumulation ----------------
// block = (v, sub); 4 waves/block, BPV blocks per node; wave handles pairs
// p = sub*4 + wave + i*4*BPV. Writes disjoint partial sums (deterministic).
__global__ __launch_bounds__(256) void pair_kernel(
    const float* __restrict__ xa, const float* __restrict__ W1a,
    const float* __restrict__ b1a, const unsigned* __restrict__ bits,
    float* __restrict__ hpart, int BPV)
{
    __shared__ unsigned rowv[NW];
    __shared__ unsigned short ulist[NN];
    __shared__ int s_deg;
    __shared__ float hsum_s[H];

    const int v = blockIdx.x / BPV, sub = blockIdx.x % BPV;
    const int t = threadIdx.x, lane = t & 63, wave = t >> 6;

    if (t < H)  hsum_s[t] = 0.f;
    if (t < NW) rowv[t] = bits[v * NW + t];
    __syncthreads();

    // parallel neighbor enumeration: lane j handles bitmask word j
    if (wave == 0 && lane < NW) {
        int off = 0;
        for (int i = 0; i < lane; ++i) off += __popc(rowv[i]);
        unsigned c = rowv[lane];
        while (c) {
            int b = __ffs(c) - 1; c &= c - 1;
            ulist[off++] = (unsigned short)(lane * 32 + b);
        }
        if (lane == NW - 1) s_deg = off;
    }
    __syncthreads();

    const int   deg = s_deg;
    const float r64 = W1a[64 * H + lane];
    const float c0  = b1a[lane] + r64;                 // b1a + 1*r64
    const float c1  = r64 + W1a[65 * H + lane];        // cnt*(r64+r65)

    float hacc = 0.f;
    for (int p = sub * 4 + wave; p < deg; p += 4 * BPV) {
        const int u = ulist[p];
        const unsigned* bu = bits + u * NW;
        int cnt = 0; float xs = 0.f;
        #pragma unroll
        for (int j = 0; j < NW; ++j) {
            unsigned c = rowv[j] & bu[j];
            cnt += __popc(c);
            while (c) {
                int b = __ffs(c) - 1; c &= c - 1;
                xs += xa[(j * 32 + b) * H + lane];      // sum of xa over common nbrs
            }
        }
        float h = xa[u * H + lane] + xs + c0 + (float)cnt * c1;
        hacc += fmaxf(h, 0.f);                          // ReLU then accumulate
    }
    atomicAdd(&hsum_s[lane], hacc);
    __syncthreads();
    if (t < H) hpart[(v * BPV + sub) * H + t] = hsum_s[t];
}

// ---------------- K3: per-node tail: agg = hsum@W1b + deg*b1b; MLP0 ----------------
__global__ __launch_bounds__(64) void tail_kernel(
    const float* __restrict__ x,
    const float* __restrict__ W1b, const float* __restrict__ b1b,
    const float* __restrict__ W0a, const float* __restrict__ b0a,
    const float* __restrict__ W0b, const float* __restrict__ b0b,
    const unsigned* __restrict__ bits, const float* __restrict__ hpart,
    float* __restrict__ out, int BPV)
{
    const int v = blockIdx.x, lane = threadIdx.x;

    int dsum = (lane < NW) ? __popc(bits[v * NW + lane]) : 0;
    #pragma unroll
    for (int off = 32; off; off >>= 1) dsum += __shfl_xor(dsum, off, 64);

    float hs = 0.f;
    for (int s = 0; s < BPV; ++s) hs += hpart[(v * BPV + s) * H + lane];

    const float fdeg = (float)dsum;
    float a = fdeg * b1b[lane];
    #pragma unroll
    for (int d = 0; d < H; ++d) a += __shfl(hs, d, 64) * W1b[d * 65 + lane];

    float p = hs * W1b[lane * 65 + 64];
    #pragma unroll
    for (int off = 32; off; off >>= 1) p += __shfl_xor(p, off, 64);
    const float agg64 = p + fdeg * b1b[64];

    const float inp = x[v * H + lane] + a;              // hv + agg (first 64)
    float h = b0a[lane] + agg64 * W0a[64 * H + lane];
    #pragma unroll
    for (int k = 0; k < H; ++k) h += __shfl(inp, k, 64) * W0a[k * H + lane];
    h = fmaxf(h, 0.f);

    float o = b0b[lane];
    #pragma unroll
    for (int d = 0; d < H; ++d) o += __shfl(h, d, 64) * W0b[d * H + lane];
    out[v * H + lane] = o;
}

extern "C" void kernel_launch(void* const* d_in, const int* in_sizes, int n_in,
                              void* d_out, int out_size, void* d_ws, size_t ws_size,
                              hipStream_t stream) {
    const float* x   = (const float*)d_in[0];
    const float* W1a = (const float*)d_in[1];
    const float* b1a = (const float*)d_in[2];
    const float* W1b = (const float*)d_in[3];
    const float* b1b = (const float*)d_in[4];
    const float* W0a = (const float*)d_in[5];
    const float* b0a = (const float*)d_in[6];
    const float* W0b = (const float*)d_in[7];
    const float* b0b = (const float*)d_in[8];
    const int*   ei  = (const int*)d_in[9];
    const int    E   = in_sizes[9] / 2;

    const size_t base = (size_t)NN * NW * 4 + (size_t)NN * H * 4;  // bits + xa
    int BPV = 1;
    if      (ws_size >= base + (size_t)NN * 4 * H * 4) BPV = 4;
    else if (ws_size >= base + (size_t)NN * 2 * H * 4) BPV = 2;

    unsigned* bits  = (unsigned*)d_ws;
    float*    xa    = (float*)((char*)d_ws + (size_t)NN * NW * 4);
    float*    hpart = (float*)((char*)d_ws + base);

    init_xa<<<NN / 4, 256, 0, stream>>>(x, W1a, bits, xa);
    build_bits<<<(E + 255) / 256, 256, 0, stream>>>(ei, E, bits);
    pair_kernel<<<NN * BPV, 256, 0, stream>>>(xa, W1a, b1a, bits, hpart, BPV);
    tail_kernel<<<NN, 64, 0, stream>>>(x, W1b, b1b, W0a, b0a, W0b, b0b,
                                       bits, hpart, (float*)d_out, BPV);
}

// Round 3
// 31.453 us; speedup vs baseline: 1.9872x; 1.0996x over previous
//
#include <hip/hip_runtime.h>

#define NN  640
#define NW  20    // 640/32 bitmask words per node
#define H   64
#define NPB 4     // nodes per block in K1

// ---------------- K1: per-block edge scan -> adjacency bitmask + xa = x @ W1a ----------------
// 160 blocks x 256 threads; block owns nodes [4b, 4b+3]. Edge list is symmetric,
// so scanning the first direction only is sufficient. No global zeroing/atomics.
__global__ __launch_bounds__(256) void build_xa(
    const int* __restrict__ ei, int E,
    const float* __restrict__ x, const float* __restrict__ W1a,
    unsigned* __restrict__ bits, float* __restrict__ xa)
{
    __shared__ unsigned sb[NPB * NW];
    const int t = threadIdx.x;
    const int v0 = blockIdx.x * NPB;

    if (t < NPB * NW) sb[t] = 0u;
    __syncthreads();

    for (int k = t; k < E; k += 256) {
        int a = ei[k];
        if ((a >> 2) == blockIdx.x) {
            int b = ei[k + E];
            if (b != a) atomicOr(&sb[(a & 3) * NW + (b >> 5)], 1u << (b & 31));
        }
    }
    __syncthreads();
    if (t < NPB * NW) bits[v0 * NW + t] = sb[t];

    // wave w computes xa row for node v0+w
    const int lane = t & 63, wave = t >> 6;
    const int v = v0 + wave;
    const float xv = x[v * H + lane];
    float acc = 0.f;
    #pragma unroll
    for (int k = 0; k < H; ++k)
        acc += __shfl(xv, k, 64) * W1a[k * H + lane];
    xa[v * H + lane] = acc;
}

// ---------------- K2: fused per-node ego computation ----------------
// block = node v; 8 waves. Pair loop over neighbors u (hidden-layer accumulation),
// LDS reduce, then wave 0 runs the linear tail + MLP0 and writes out[v].
__global__ __launch_bounds__(512) void fused(
    const float* __restrict__ x,  const float* __restrict__ xa,
    const float* __restrict__ W1a, const float* __restrict__ b1a,
    const float* __restrict__ W1b, const float* __restrict__ b1b,
    const float* __restrict__ W0a, const float* __restrict__ b0a,
    const float* __restrict__ W0b, const float* __restrict__ b0b,
    const unsigned* __restrict__ bits,
    float* __restrict__ out)
{
    __shared__ __align__(16) unsigned rowv[NW];
    __shared__ unsigned short ulist[NN];
    __shared__ int s_deg;
    __shared__ float hsum[H];

    const int v = blockIdx.x, t = threadIdx.x;
    const int lane = t & 63, wave = t >> 6;

    if (t < H)  hsum[t] = 0.f;
    if (t < NW) rowv[t] = bits[v * NW + t];
    __syncthreads();

    // parallel neighbor enumeration (lane j owns bitmask word j)
    if (wave == 0 && lane < NW) {
        int off = 0;
        for (int i = 0; i < lane; ++i) off += __popc(rowv[i]);
        unsigned c = rowv[lane];
        while (c) {
            int b = __ffs(c) - 1; c &= c - 1;
            ulist[off++] = (unsigned short)(lane * 32 + b);
        }
        if (lane == NW - 1) s_deg = off;
    }
    __syncthreads();

    const int   deg = s_deg;
    const float r64 = W1a[64 * H + lane];
    const float c0  = b1a[lane] + r64;            // b1a + 1*W1a[64]
    const float c1  = r64 + W1a[65 * H + lane];   // per-cnt term

    const uint4* rv4 = (const uint4*)rowv;
    const uint4 r0 = rv4[0], r1 = rv4[1], r2 = rv4[2], r3 = rv4[3], r4 = rv4[4];

    float hacc = 0.f;
    for (int p = wave; p < deg; p += 8) {
        const int u = ulist[p];
        const uint4* bu = (const uint4*)(bits + u * NW);
        const uint4 q0 = bu[0], q1 = bu[1], q2 = bu[2], q3 = bu[3], q4 = bu[4];
        unsigned cw[NW] = {
            r0.x & q0.x, r0.y & q0.y, r0.z & q0.z, r0.w & q0.w,
            r1.x & q1.x, r1.y & q1.y, r1.z & q1.z, r1.w & q1.w,
            r2.x & q2.x, r2.y & q2.y, r2.z & q2.z, r2.w & q2.w,
            r3.x & q3.x, r3.y & q3.y, r3.z & q3.z, r3.w & q3.w,
            r4.x & q4.x, r4.y & q4.y, r4.z & q4.z, r4.w & q4.w };
        int cnt = 0;
        #pragma unroll
        for (int j = 0; j < NW; ++j) cnt += __popc(cw[j]);
        float xs = 0.f;
        #pragma unroll
        for (int j = 0; j < NW; ++j) {
            unsigned c = cw[j];
            while (c) {
                int b = __ffs(c) - 1; c &= c - 1;
                xs += xa[(j * 32 + b) * H + lane];   // sum of xa over common nbrs
            }
        }
        float h = xa[u * H + lane] + xs + c0 + (float)cnt * c1;
        hacc += fmaxf(h, 0.f);                       // ReLU then accumulate
    }
    atomicAdd(&hsum[lane], hacc);
    __syncthreads();

    // ---- tail on wave 0: agg = hsum@W1b + deg*b1b; then MLP0 ----
    if (wave == 0) {
        const float fdeg = (float)deg;
        const float hs = hsum[lane];

        float a = fdeg * b1b[lane];
        #pragma unroll
        for (int d = 0; d < H; ++d) a += __shfl(hs, d, 64) * W1b[d * 65 + lane];

        float pp = hs * W1b[lane * 65 + 64];
        #pragma unroll
        for (int off = 32; off; off >>= 1) pp += __shfl_xor(pp, off, 64);
        const float agg64 = pp + fdeg * b1b[64];

        const float inp = x[v * H + lane] + a;       // hv + agg (first 64)
        float h = b0a[lane] + agg64 * W0a[64 * H + lane];
        #pragma unroll
        for (int k = 0; k < H; ++k) h += __shfl(inp, k, 64) * W0a[k * H + lane];
        h = fmaxf(h, 0.f);

        float o = b0b[lane];
        #pragma unroll
        for (int d = 0; d < H; ++d) o += __shfl(h, d, 64) * W0b[d * H + lane];
        out[v * H + lane] = o;
    }
}

extern "C" void kernel_launch(void* const* d_in, const int* in_sizes, int n_in,
                              void* d_out, int out_size, void* d_ws, size_t ws_size,
                              hipStream_t stream) {
    const float* x   = (const float*)d_in[0];
    const float* W1a = (const float*)d_in[1];
    const float* b1a = (const float*)d_in[2];
    const float* W1b = (const float*)d_in[3];
    const float* b1b = (const float*)d_in[4];
    const float* W0a = (const float*)d_in[5];
    const float* b0a = (const float*)d_in[6];
    const float* W0b = (const float*)d_in[7];
    const float* b0b = (const float*)d_in[8];
    const int*   ei  = (const int*)d_in[9];
    const int    E   = in_sizes[9] / 2;

    unsigned* bits = (unsigned*)d_ws;
    float*    xa   = (float*)((char*)d_ws + (size_t)NN * NW * 4);

    build_xa<<<NN / NPB, 256, 0, stream>>>(ei, E, x, W1a, bits, xa);
    fused<<<NN, 512, 0, stream>>>(x, xa, W1a, b1a, W1b, b1b,
                                  W0a, b0a, W0b, b0b, bits, (float*)d_out);
}